// Round 2
// 106.335 us; speedup vs baseline: 1.0128x; 1.0128x over previous
//
#include <hip/hip_runtime.h>

// NeRF fused kernel for MI355X (gfx950) — round 7 (resubmit; round-1 bench
// was an infra failure, no signal).
// Round 6 post-mortem: main kernel is issue/latency-bound at 2 waves/SIMD
// (124 VGPR + 128 AGPR acc[8][4] live through all of phase 2 -> ~250 unified
// regs). MfmaUtil 35.6 + VALUBusy 39.3 barely overlap because phase 2 is a
// pure-MFMA burst and phase 3 a pure-VALU burst, in lockstep across the 2
// resident waves.
// Round 7 restructure: mt-pair (ks3) OUTER loop, phase 3 fused per ks3:
//   for ks3: init acc[2] from b2 (bias folded) -> 32 phase-2 MFMAs over all
//   ks2 (B-operands hb[ks2][tr] precomputed, resident: 64 VGPR) -> pack ->
//   phase-3 MFMA into acc3 (b3 folded into init).
// Acc live set 128 -> 48; peak ~155 regs -> __launch_bounds__(256,3) = 3
// waves/SIMD. Render-phase shuffle scan/reductions replaced with gfx9 DPP
// (row_shr 1/2/4/8 + row_bcast 15/31) — no ds_bpermute chains.
// Permutation identity unchanged (HW-verified in rounds 4-6):
//   h2 feature(slot) = 32*quad + mt*4 + r  (phase-2 D)  =  32*quad + ks3*8 + j
//   (phase-3 B), so phase-2 output regs ARE phase-3 B-frags.

typedef _Float16 f16;
typedef __attribute__((ext_vector_type(2))) _Float16 h2v;
typedef __attribute__((ext_vector_type(8))) _Float16 half8;
typedef __attribute__((ext_vector_type(4))) float floatx4;

#define H 128
#define NS 64

static __device__ __forceinline__ h2v pkrtz(float a, float b) {
  return __builtin_bit_cast(h2v, __builtin_amdgcn_cvt_pkrtz(a, b));
}

// x += dpp_shifted(x) with 0-fill; CTRL/RM compile-time (builtin needs ICE).
template <int CTRL, int RM>
static __device__ __forceinline__ float dpp_add(float x) {
  int sh = __builtin_amdgcn_update_dpp(0, __builtin_bit_cast(int, x),
                                       CTRL, RM, 0xf, false);
  return x + __builtin_bit_cast(float, sh);
}

// Wave64 inclusive add-scan, pure VALU (classic gfx9 sequence).
static __device__ __forceinline__ float wave_iscan(float x) {
  x = dpp_add<0x111, 0xf>(x);   // row_shr:1
  x = dpp_add<0x112, 0xf>(x);   // row_shr:2
  x = dpp_add<0x114, 0xf>(x);   // row_shr:4
  x = dpp_add<0x118, 0xf>(x);   // row_shr:8
  x = dpp_add<0x142, 0xa>(x);   // row_bcast:15 -> rows 1,3
  x = dpp_add<0x143, 0xc>(x);   // row_bcast:31 -> rows 2,3
  return x;
}

// ---------------------------------------------------------------------------
// Setup (W2/W3 parts verbatim from round 6, HW-verified): W2 -> A-frags with
// permuted cols n = 32*(l16>>2) + mt*4 + (l16&3); W3 -> A-frags with matching
// permuted rows k3 = 32*(lane>>4) + ks*8 + j (cols padded to 16).
// wsB2 dropped: b2/b3 are folded into accumulator init inside nerf_main.
// ---------------------------------------------------------------------------
__global__ void nerf_setup(const float* __restrict__ W2, const float* __restrict__ W3,
                           f16* __restrict__ wsW2, f16* __restrict__ wsW3) {
  int t = blockIdx.x * blockDim.x + threadIdx.x;
  if (t < 8192) {                       // W2 frags
    int j2 = t & 3, lane = (t >> 2) & 63, mt = (t >> 8) & 7, ks = t >> 11;
    int l16 = lane & 15;
    int k = ks * 32 + ((lane >> 4) * 8) + 2 * j2;
    int n = 32 * (l16 >> 2) + mt * 4 + (l16 & 3);    // permuted column
    wsW2[2 * t]     = (f16)W2[k * H + n];
    wsW2[2 * t + 1] = (f16)W2[(k + 1) * H + n];
  } else if (t < 9216) {                // W3 frags (A-layout, permuted rows, padded)
    int u = t - 8192;
    int j2 = u & 3, lane = (u >> 2) & 63, ks = u >> 8;
    int c = lane & 15;
    int k3 = 32 * (lane >> 4) + ks * 8 + 2 * j2;     // permuted h2 feature
    wsW3[2 * u]     = (c < 4) ? (f16)W3[k3 * 4 + c]       : (f16)0.0f;
    wsW3[2 * u + 1] = (c < 4) ? (f16)W3[(k3 + 1) * 4 + c] : (f16)0.0f;
  }
}

// ---------------------------------------------------------------------------
// Main: block = 4 rays = 4 waves; wave = 1 ray = 64 points; no barriers.
// ---------------------------------------------------------------------------
__global__ __launch_bounds__(256, 3) void nerf_main(
    const float* __restrict__ origins, const float* __restrict__ dirs,
    const float* __restrict__ W1, const float* __restrict__ b1,
    const float* __restrict__ b2, const float* __restrict__ b3,
    const f16* __restrict__ wsW2, const f16* __restrict__ wsW3,
    float* __restrict__ out)
{
  __shared__ __align__(16) f16   popd[4][2][H];   // per-wave po/pd strips (2 KB)
  __shared__ __align__(16) float f_lds[4][64][4]; // render transpose (4 KB)

  const int t = threadIdx.x;
  const int w = t >> 6, lane = t & 63, quad = lane >> 4, l16 = lane & 15;
  const float delta = 4.0f / NS;       // near=2, far=6 baked
  const int ray = blockIdx.x * 4 + w;

  // ---- po/pd: po[k] = o@W1[:,k]+b1[k], pd[k] = d@W1[:,k]; f16 to LDS ----
  {
    const float o0 = origins[ray*3], o1 = origins[ray*3+1], o2 = origins[ray*3+2];
    const float d0 = dirs[ray*3],    d1 = dirs[ray*3+1],    d2 = dirs[ray*3+2];
    const int k0 = lane * 2;
    const float2 wr0 = *(const float2*)&W1[0*H + k0];
    const float2 wr1 = *(const float2*)&W1[1*H + k0];
    const float2 wr2 = *(const float2*)&W1[2*H + k0];
    const float2 bb  = *(const float2*)&b1[k0];
    float poa = fmaf(o2, wr2.x, fmaf(o1, wr1.x, fmaf(o0, wr0.x, bb.x)));
    float pob = fmaf(o2, wr2.y, fmaf(o1, wr1.y, fmaf(o0, wr0.y, bb.y)));
    float pda = fmaf(d2, wr2.x, fmaf(d1, wr1.x, d0 * wr0.x));
    float pdb = fmaf(d2, wr2.y, fmaf(d1, wr1.y, d0 * wr0.y));
    h2v po2; po2[0] = (f16)poa; po2[1] = (f16)pob;
    h2v pd2; pd2[0] = (f16)pda; pd2[1] = (f16)pdb;
    *(h2v*)&popd[w][0][k0] = po2;
    *(h2v*)&popd[w][1][k0] = pd2;
  }

  // ---- hb precompute: hb[ks2][tr] = relu(po + m*pd), resident 64 VGPRs ----
  // m exact in f16 (multiple of 1/32); sample s = tr*16 + l16.
  half8 hb[4][4];
  {
    const half8 z8 = (half8)(f16)0.0f;
    half8 m8[4];
    #pragma unroll
    for (int tr = 0; tr < 4; ++tr)
      m8[tr] = (half8)(f16)(2.0f + (tr*16 + l16 + 0.5f) * delta);
    #pragma unroll
    for (int ks = 0; ks < 4; ++ks) {
      const half8 po8 = *(const half8*)&popd[w][0][ks*32 + quad*8];
      const half8 pd8 = *(const half8*)&popd[w][1][ks*32 + quad*8];
      #pragma unroll
      for (int tr = 0; tr < 4; ++tr)
        hb[ks][tr] = __builtin_elementwise_max(pd8 * m8[tr] + po8, z8);
    }
  }

  const half8* w2f = (const half8*)wsW2;
  const half8* w3f = (const half8*)wsW3;
  const h2v z2 = (h2v)(f16)0.0f;

  // acc3 init = b3 broadcast (quad 0 rows are the only consumed ones; W3
  // cols >=4 are zero-padded so other quads are garbage-but-unused).
  floatx4 acc3[4];
  {
    const float4 b3v = *(const float4*)&b3[0];
    #pragma unroll
    for (int tr = 0; tr < 4; ++tr) {
      acc3[tr][0] = b3v.x; acc3[tr][1] = b3v.y;
      acc3[tr][2] = b3v.z; acc3[tr][3] = b3v.w;
    }
  }

  // ---- Fused phase 2+3, mt-pair outer: per ks3 compute only features
  // 32*quad + 8*ks3 + 0..7 (acc pair), then immediately consume them as the
  // phase-3 B-frag. Rolled loop (4 iters) to contain register pressure. ----
  #pragma unroll 1
  for (int ks3 = 0; ks3 < 4; ++ks3) {
    const int mt0 = 2 * ks3, mt1 = mt0 + 1;
    // bias fold: acc[mt][tr][r] starts at b2[32*quad + 4*mt + r]
    const float4 bA = *(const float4*)&b2[quad*32 + mt0*4];
    const float4 bB = *(const float4*)&b2[quad*32 + mt1*4];
    const half8 w3k = w3f[ks3*64 + lane];
    floatx4 accA[4], accB[4];
    #pragma unroll
    for (int tr = 0; tr < 4; ++tr) {
      accA[tr][0] = bA.x; accA[tr][1] = bA.y; accA[tr][2] = bA.z; accA[tr][3] = bA.w;
      accB[tr][0] = bB.x; accB[tr][1] = bB.y; accB[tr][2] = bB.z; accB[tr][3] = bB.w;
    }
    #pragma unroll
    for (int ks2 = 0; ks2 < 4; ++ks2) {
      const half8 wA = w2f[(ks2*8 + mt0)*64 + lane];
      const half8 wB = w2f[(ks2*8 + mt1)*64 + lane];
      #pragma unroll
      for (int tr = 0; tr < 4; ++tr) {
        accA[tr] = __builtin_amdgcn_mfma_f32_16x16x32_f16(wA, hb[ks2][tr], accA[tr], 0, 0, 0);
        accB[tr] = __builtin_amdgcn_mfma_f32_16x16x32_f16(wB, hb[ks2][tr], accB[tr], 0, 0, 0);
      }
    }
    // pack (bias already in acc) + phase-3 MFMA; b covers features
    // 32*quad + 8*ks3 + 0..7 matching W3's permuted rows.
    #pragma unroll
    for (int tr = 0; tr < 4; ++tr) {
      h2v c0 = __builtin_elementwise_max(pkrtz(accA[tr][0], accA[tr][1]), z2);
      h2v c1 = __builtin_elementwise_max(pkrtz(accA[tr][2], accA[tr][3]), z2);
      h2v c2 = __builtin_elementwise_max(pkrtz(accB[tr][0], accB[tr][1]), z2);
      h2v c3 = __builtin_elementwise_max(pkrtz(accB[tr][2], accB[tr][3]), z2);
      half8 b = { c0[0], c0[1], c1[0], c1[1], c2[0], c2[1], c3[0], c3[1] };
      acc3[tr] = __builtin_amdgcn_mfma_f32_16x16x32_f16(w3k, b, acc3[tr], 0, 0, 0);
    }
  }

  // D3: lane holds f[m = quad*4+r][point tr*16+l16]; quad 0 rows 0..3 are
  // (R,G,B,sigma), b3 already folded in. Transpose via tiny f_lds (same
  // wave, no barrier).
  if (quad == 0) {
    #pragma unroll
    for (int tr = 0; tr < 4; ++tr) {
      float4 fv;
      fv.x = acc3[tr][0]; fv.y = acc3[tr][1];
      fv.z = acc3[tr][2]; fv.w = acc3[tr][3];
      *(float4*)&f_lds[w][tr*16 + l16][0] = fv;      // ds_write_b128
    }
  }

  // ---- Phase 4: volume rendering, lane = sample; DPP scan, no bpermute ----
  {
    const float4 fv = *(const float4*)&f_lds[w][lane][0];
    const float sigma = fv.w;
    const float alpha = 1.0f - __expf(-sigma * delta);
    const float S  = wave_iscan(sigma);              // inclusive prefix
    const float T  = __expf(-delta * (S - sigma));   // exclusive transmittance
    const float wt = alpha * T;
    const float sr = wave_iscan(wt * fv.x);          // lane 63 = total
    const float sg = wave_iscan(wt * fv.y);
    const float sb = wave_iscan(wt * fv.z);
    if (lane == 63) {
      out[ray*3+0] = sr; out[ray*3+1] = sg; out[ray*3+2] = sb;
    }
  }
}

extern "C" void kernel_launch(void* const* d_in, const int* in_sizes, int n_in,
                              void* d_out, int out_size, void* d_ws, size_t ws_size,
                              hipStream_t stream) {
  const float* origins = (const float*)d_in[0];
  const float* dirs    = (const float*)d_in[1];
  const float* W1      = (const float*)d_in[2];
  const float* b1      = (const float*)d_in[3];
  const float* W2      = (const float*)d_in[4];
  const float* b2      = (const float*)d_in[5];
  const float* W3      = (const float*)d_in[6];
  const float* b3      = (const float*)d_in[7];
  float* out = (float*)d_out;

  f16* wsW2 = (f16*)d_ws;          // 16384 f16 = 32 KB
  f16* wsW3 = wsW2 + 16384;        // 2048 f16  = 4 KB

  nerf_setup<<<36, 256, 0, stream>>>(W2, W3, wsW2, wsW3);
  nerf_main<<<16384 / 4, 256, 0, stream>>>(
      origins, dirs, W1, b1, b2, b3, wsW2, wsW3, out);
}

// Round 3
// 102.579 us; speedup vs baseline: 1.0499x; 1.0366x over previous
//
#include <hip/hip_runtime.h>

// NeRF fused kernel for MI355X (gfx950) — round 8.
// Round 7 post-mortem: ks3-outer restructure + DPP scan landed (VGPR 124->68,
// occupancy 18->25%, no spill) but dur only 43.5->42.1 us and MfmaUtil stuck
// at 36%. Occupancy was NOT the binder. Real binder: every wave re-reads the
// whole 36 KB W2/W3 frag workspace from GLOBAL (L2) — 590 MB of L2 traffic
// (~14 TB/s) as 36 latency-exposed global_load_dwordx4 per wave, serialized
// against each ks3's MFMA burst.
// Round 8: block = 512 threads = 8 rays. Stage wsW2+wsW3 (36 KB, contiguous)
// + b2 (512 B) into LDS once per block (cooperative copy, one barrier); all
// in-loop weight reads become ds_read_b128 (conflict-free contiguous 1 KB per
// wave). LDS/block ~48.5 KB -> 3 blocks/CU; ~116 unified regs -> 4 waves/SIMD.
// Everything else (frag permutation, bias folds, DPP scan) verbatim from r7.
// Permutation identity (HW-verified rounds 4-7):
//   h2 feature(slot) = 32*quad + mt*4 + r  (phase-2 D)  =  32*quad + ks3*8 + j
//   (phase-3 B), so phase-2 output regs ARE phase-3 B-frags.

typedef _Float16 f16;
typedef __attribute__((ext_vector_type(2))) _Float16 h2v;
typedef __attribute__((ext_vector_type(8))) _Float16 half8;
typedef __attribute__((ext_vector_type(4))) float floatx4;

#define H 128
#define NS 64

static __device__ __forceinline__ h2v pkrtz(float a, float b) {
  return __builtin_bit_cast(h2v, __builtin_amdgcn_cvt_pkrtz(a, b));
}

// x += dpp_shifted(x) with 0-fill; CTRL/RM compile-time (builtin needs ICE).
template <int CTRL, int RM>
static __device__ __forceinline__ float dpp_add(float x) {
  int sh = __builtin_amdgcn_update_dpp(0, __builtin_bit_cast(int, x),
                                       CTRL, RM, 0xf, false);
  return x + __builtin_bit_cast(float, sh);
}

// Wave64 inclusive add-scan, pure VALU (classic gfx9 sequence).
static __device__ __forceinline__ float wave_iscan(float x) {
  x = dpp_add<0x111, 0xf>(x);   // row_shr:1
  x = dpp_add<0x112, 0xf>(x);   // row_shr:2
  x = dpp_add<0x114, 0xf>(x);   // row_shr:4
  x = dpp_add<0x118, 0xf>(x);   // row_shr:8
  x = dpp_add<0x142, 0xa>(x);   // row_bcast:15 -> rows 1,3
  x = dpp_add<0x143, 0xc>(x);   // row_bcast:31 -> rows 2,3
  return x;
}

// ---------------------------------------------------------------------------
// Setup (verbatim from rounds 6/7, HW-verified): W2 -> A-frags with permuted
// cols n = 32*(l16>>2) + mt*4 + (l16&3); W3 -> A-frags with matching permuted
// rows k3 = 32*(lane>>4) + ks*8 + j (cols padded to 16).
// ---------------------------------------------------------------------------
__global__ void nerf_setup(const float* __restrict__ W2, const float* __restrict__ W3,
                           f16* __restrict__ wsW2, f16* __restrict__ wsW3) {
  int t = blockIdx.x * blockDim.x + threadIdx.x;
  if (t < 8192) {                       // W2 frags
    int j2 = t & 3, lane = (t >> 2) & 63, mt = (t >> 8) & 7, ks = t >> 11;
    int l16 = lane & 15;
    int k = ks * 32 + ((lane >> 4) * 8) + 2 * j2;
    int n = 32 * (l16 >> 2) + mt * 4 + (l16 & 3);    // permuted column
    wsW2[2 * t]     = (f16)W2[k * H + n];
    wsW2[2 * t + 1] = (f16)W2[(k + 1) * H + n];
  } else if (t < 9216) {                // W3 frags (A-layout, permuted rows, padded)
    int u = t - 8192;
    int j2 = u & 3, lane = (u >> 2) & 63, ks = u >> 8;
    int c = lane & 15;
    int k3 = 32 * (lane >> 4) + ks * 8 + 2 * j2;     // permuted h2 feature
    wsW3[2 * u]     = (c < 4) ? (f16)W3[k3 * 4 + c]       : (f16)0.0f;
    wsW3[2 * u + 1] = (c < 4) ? (f16)W3[(k3 + 1) * 4 + c] : (f16)0.0f;
  }
}

// ---------------------------------------------------------------------------
// Main: block = 8 rays = 8 waves; wave = 1 ray = 64 points.
// One barrier (after LDS weight staging); no other cross-wave deps.
// ---------------------------------------------------------------------------
__global__ __launch_bounds__(512, 4) void nerf_main(
    const float* __restrict__ origins, const float* __restrict__ dirs,
    const float* __restrict__ W1, const float* __restrict__ b1,
    const float* __restrict__ b2, const float* __restrict__ b3,
    const f16* __restrict__ ws,          // wsW2 (32 KB) ++ wsW3 (4 KB)
    float* __restrict__ out)
{
  __shared__ __align__(16) half8 w_lds[2304];     // 36 KB: W2 frags [0..2047], W3 [2048..2303]
  __shared__ __align__(16) float b2_lds[H];       // 512 B
  __shared__ __align__(16) f16   popd[8][2][H];   // per-wave po/pd strips (4 KB)
  __shared__ __align__(16) float f_lds[8][64][4]; // render transpose (8 KB)

  const int t = threadIdx.x;
  const int w = t >> 6, lane = t & 63, quad = lane >> 4, l16 = lane & 15;
  const float delta = 4.0f / NS;       // near=2, far=6 baked
  const int ray = blockIdx.x * 8 + w;

  // ---- Stage weights into LDS (2304 x 16 B = 4.5 per thread) ----
  {
    const uint4* src = (const uint4*)ws;
    uint4* dst = (uint4*)w_lds;
    #pragma unroll
    for (int i = 0; i < 4; ++i) dst[t + i * 512] = src[t + i * 512];
    if (t < 256) dst[t + 2048] = src[t + 2048];
    if (t < 32)  ((float4*)b2_lds)[t] = ((const float4*)b2)[t];
  }

  // ---- po/pd: po[k] = o@W1[:,k]+b1[k], pd[k] = d@W1[:,k]; f16 to LDS ----
  {
    const float o0 = origins[ray*3], o1 = origins[ray*3+1], o2 = origins[ray*3+2];
    const float d0 = dirs[ray*3],    d1 = dirs[ray*3+1],    d2 = dirs[ray*3+2];
    const int k0 = lane * 2;
    const float2 wr0 = *(const float2*)&W1[0*H + k0];
    const float2 wr1 = *(const float2*)&W1[1*H + k0];
    const float2 wr2 = *(const float2*)&W1[2*H + k0];
    const float2 bb  = *(const float2*)&b1[k0];
    float poa = fmaf(o2, wr2.x, fmaf(o1, wr1.x, fmaf(o0, wr0.x, bb.x)));
    float pob = fmaf(o2, wr2.y, fmaf(o1, wr1.y, fmaf(o0, wr0.y, bb.y)));
    float pda = fmaf(d2, wr2.x, fmaf(d1, wr1.x, d0 * wr0.x));
    float pdb = fmaf(d2, wr2.y, fmaf(d1, wr1.y, d0 * wr0.y));
    h2v po2; po2[0] = (f16)poa; po2[1] = (f16)pob;
    h2v pd2; pd2[0] = (f16)pda; pd2[1] = (f16)pdb;
    *(h2v*)&popd[w][0][k0] = po2;
    *(h2v*)&popd[w][1][k0] = pd2;
  }

  // ---- hb precompute: hb[ks2][tr] = relu(po + m*pd), resident 64 VGPRs ----
  // m exact in f16 (multiple of 1/32); sample s = tr*16 + l16.
  half8 hb[4][4];
  {
    const half8 z8 = (half8)(f16)0.0f;
    half8 m8[4];
    #pragma unroll
    for (int tr = 0; tr < 4; ++tr)
      m8[tr] = (half8)(f16)(2.0f + (tr*16 + l16 + 0.5f) * delta);
    #pragma unroll
    for (int ks = 0; ks < 4; ++ks) {
      const half8 po8 = *(const half8*)&popd[w][0][ks*32 + quad*8];
      const half8 pd8 = *(const half8*)&popd[w][1][ks*32 + quad*8];
      #pragma unroll
      for (int tr = 0; tr < 4; ++tr)
        hb[ks][tr] = __builtin_elementwise_max(pd8 * m8[tr] + po8, z8);
    }
  }

  __syncthreads();                       // weights staged

  const half8* w2f = w_lds;              // 2048 frags
  const half8* w3f = w_lds + 2048;       // 256 frags
  const h2v z2 = (h2v)(f16)0.0f;

  // acc3 init = b3 broadcast (quad 0 rows are the only consumed ones; W3
  // cols >=4 are zero-padded so other quads are garbage-but-unused).
  floatx4 acc3[4];
  {
    const float4 b3v = *(const float4*)&b3[0];
    #pragma unroll
    for (int tr = 0; tr < 4; ++tr) {
      acc3[tr][0] = b3v.x; acc3[tr][1] = b3v.y;
      acc3[tr][2] = b3v.z; acc3[tr][3] = b3v.w;
    }
  }

  // ---- Fused phase 2+3, mt-pair outer: per ks3 compute only features
  // 32*quad + 8*ks3 + 0..7 (acc pair), then immediately consume them as the
  // phase-3 B-frag. Rolled loop (4 iters) to contain register pressure. ----
  #pragma unroll 1
  for (int ks3 = 0; ks3 < 4; ++ks3) {
    const int mt0 = 2 * ks3, mt1 = mt0 + 1;
    // bias fold: acc[mt][tr][r] starts at b2[32*quad + 4*mt + r]
    const float4 bA = *(const float4*)&b2_lds[quad*32 + mt0*4];
    const float4 bB = *(const float4*)&b2_lds[quad*32 + mt1*4];
    const half8 w3k = w3f[ks3*64 + lane];
    floatx4 accA[4], accB[4];
    #pragma unroll
    for (int tr = 0; tr < 4; ++tr) {
      accA[tr][0] = bA.x; accA[tr][1] = bA.y; accA[tr][2] = bA.z; accA[tr][3] = bA.w;
      accB[tr][0] = bB.x; accB[tr][1] = bB.y; accB[tr][2] = bB.z; accB[tr][3] = bB.w;
    }
    #pragma unroll
    for (int ks2 = 0; ks2 < 4; ++ks2) {
      const half8 wA = w2f[(ks2*8 + mt0)*64 + lane];
      const half8 wB = w2f[(ks2*8 + mt1)*64 + lane];
      #pragma unroll
      for (int tr = 0; tr < 4; ++tr) {
        accA[tr] = __builtin_amdgcn_mfma_f32_16x16x32_f16(wA, hb[ks2][tr], accA[tr], 0, 0, 0);
        accB[tr] = __builtin_amdgcn_mfma_f32_16x16x32_f16(wB, hb[ks2][tr], accB[tr], 0, 0, 0);
      }
    }
    // pack (bias already in acc) + phase-3 MFMA; b covers features
    // 32*quad + 8*ks3 + 0..7 matching W3's permuted rows.
    #pragma unroll
    for (int tr = 0; tr < 4; ++tr) {
      h2v c0 = __builtin_elementwise_max(pkrtz(accA[tr][0], accA[tr][1]), z2);
      h2v c1 = __builtin_elementwise_max(pkrtz(accA[tr][2], accA[tr][3]), z2);
      h2v c2 = __builtin_elementwise_max(pkrtz(accB[tr][0], accB[tr][1]), z2);
      h2v c3 = __builtin_elementwise_max(pkrtz(accB[tr][2], accB[tr][3]), z2);
      half8 b = { c0[0], c0[1], c1[0], c1[1], c2[0], c2[1], c3[0], c3[1] };
      acc3[tr] = __builtin_amdgcn_mfma_f32_16x16x32_f16(w3k, b, acc3[tr], 0, 0, 0);
    }
  }

  // D3: lane holds f[m = quad*4+r][point tr*16+l16]; quad 0 rows 0..3 are
  // (R,G,B,sigma), b3 already folded in. Transpose via tiny f_lds (same
  // wave, no barrier).
  if (quad == 0) {
    #pragma unroll
    for (int tr = 0; tr < 4; ++tr) {
      float4 fv;
      fv.x = acc3[tr][0]; fv.y = acc3[tr][1];
      fv.z = acc3[tr][2]; fv.w = acc3[tr][3];
      *(float4*)&f_lds[w][tr*16 + l16][0] = fv;      // ds_write_b128
    }
  }

  // ---- Phase 4: volume rendering, lane = sample; DPP scan, no bpermute ----
  {
    const float4 fv = *(const float4*)&f_lds[w][lane][0];
    const float sigma = fv.w;
    const float alpha = 1.0f - __expf(-sigma * delta);
    const float S  = wave_iscan(sigma);              // inclusive prefix
    const float T  = __expf(-delta * (S - sigma));   // exclusive transmittance
    const float wt = alpha * T;
    const float sr = wave_iscan(wt * fv.x);          // lane 63 = total
    const float sg = wave_iscan(wt * fv.y);
    const float sb = wave_iscan(wt * fv.z);
    if (lane == 63) {
      out[ray*3+0] = sr; out[ray*3+1] = sg; out[ray*3+2] = sb;
    }
  }
}

extern "C" void kernel_launch(void* const* d_in, const int* in_sizes, int n_in,
                              void* d_out, int out_size, void* d_ws, size_t ws_size,
                              hipStream_t stream) {
  const float* origins = (const float*)d_in[0];
  const float* dirs    = (const float*)d_in[1];
  const float* W1      = (const float*)d_in[2];
  const float* b1      = (const float*)d_in[3];
  const float* W2      = (const float*)d_in[4];
  const float* b2      = (const float*)d_in[5];
  const float* W3      = (const float*)d_in[6];
  const float* b3      = (const float*)d_in[7];
  float* out = (float*)d_out;

  f16* wsW2 = (f16*)d_ws;          // 16384 f16 = 32 KB
  f16* wsW3 = wsW2 + 16384;        // 2048 f16  = 4 KB (contiguous with wsW2)

  nerf_setup<<<36, 256, 0, stream>>>(W2, W3, wsW2, wsW3);
  nerf_main<<<16384 / 8, 512, 0, stream>>>(
      origins, dirs, W1, b1, b2, b3, wsW2, out);
}